// Round 1
// baseline (782.605 us; speedup 1.0000x reference)
//
#include <hip/hip_runtime.h>

// RelativeAttention: B=8, N=2048, D=512, fp32 in, (out[B,N,D], p[B,N,N]) fp32 out.
//
// Plan:
//   S[b,i,j] = q.k (GEMM1) + q.w_k[(N-1)-i+j] (GEMM2, band trick: per 128-row
//   i-tile all needed w_k rows form a contiguous band of width N+127; computed
//   as a standard NT GEMM over band columns bc, scattered with j = bc + i' - 127).
//   p = softmax(S) in-place (S lives in the p region of d_out).
//   out = p.v + skew(p).w_v  (GEMM3, two K-loops; B-operands from f16 transposed
//   copies vT[B,D,N], wvT[512,4096(pad)] staged in d_ws -> needs ~21 MB ws).
//
// All matmuls: mfma_f32_16x16x32_f16, fp32 accum. fp16 chosen over bf16 for
// 8x tighter input rounding (score err ~0.02 sigma vs threshold 0.1475).
// LDS tiles [128][32] f16, XOR swizzle on byte bits 4..5 with row bits 1..2:
// keeps b128 reads 16B-aligned, cuts frag-read bank conflicts 8-way -> 2-way.

#define SEQN 2048
#define DD   512
#define NB   8
#define WROWS 4095   // 2N-1
#define WPAD  4096   // padded row stride for wvT (8B-aligned f16 rows)

typedef float     f32x4 __attribute__((ext_vector_type(4)));
typedef _Float16  h16x4 __attribute__((ext_vector_type(4)));
typedef _Float16  h16x8 __attribute__((ext_vector_type(8)));

__device__ __forceinline__ unsigned swzw(int row, int c4) {
  unsigned b = (unsigned)(row * 64 + c4 * 8);
  return b ^ (((unsigned)row & 6u) << 3);
}
__device__ __forceinline__ unsigned swzr(int row, int kg) {
  unsigned b = (unsigned)(row * 64 + kg * 16);
  return b ^ (((unsigned)row & 6u) << 3);
}

// ---------------- transpose v [B,N,D] f32 -> vT [B,D,N] f16 ----------------
__global__ __launch_bounds__(256) void transpose_v_k(const float* __restrict__ v,
                                                     _Float16* __restrict__ vT) {
  __shared__ float tile[32][33];
  const int d0 = blockIdx.x * 32, j0 = blockIdx.y * 32, b = blockIdx.z;
  const int tid = threadIdx.x;
#pragma unroll
  for (int rep = 0; rep < 4; rep++) {
    int idx = rep * 256 + tid;
    int rr = idx >> 5, cc = idx & 31;
    tile[rr][cc] = v[((size_t)(b * SEQN + j0 + rr)) * DD + d0 + cc];
  }
  __syncthreads();
#pragma unroll
  for (int rep = 0; rep < 4; rep++) {
    int idx = rep * 256 + tid;
    int rr = idx >> 5, cc = idx & 31;
    vT[((size_t)(b * DD + d0 + rr)) * SEQN + j0 + cc] = (_Float16)tile[cc][rr];
  }
}

// ------------- transpose w_v [4095,512] f32 -> wvT [512,4096] f16 -----------
__global__ __launch_bounds__(256) void transpose_wv_k(const float* __restrict__ wv,
                                                      _Float16* __restrict__ wvT) {
  __shared__ float tile[32][33];
  const int d0 = blockIdx.x * 32, r0 = blockIdx.y * 32;
  const int tid = threadIdx.x;
#pragma unroll
  for (int rep = 0; rep < 4; rep++) {
    int idx = rep * 256 + tid;
    int rr = idx >> 5, cc = idx & 31;
    float val = 0.f;
    if (r0 + rr < WROWS) val = wv[(size_t)(r0 + rr) * DD + d0 + cc];
    tile[rr][cc] = val;
  }
  __syncthreads();
#pragma unroll
  for (int rep = 0; rep < 4; rep++) {
    int idx = rep * 256 + tid;
    int rr = idx >> 5, cc = idx & 31;
    wvT[(size_t)(d0 + rr) * WPAD + r0 + cc] = (_Float16)tile[cc][rr];
  }
}

// ---------------- base scores: S[b,i,j] = sum_d q[b,i,d] k[b,j,d] -----------
__global__ __launch_bounds__(256) void score_base_k(const float* __restrict__ q,
                                                    const float* __restrict__ kmat,
                                                    float* __restrict__ S) {
  __shared__ __align__(16) char smem[16384];
  const int j0 = blockIdx.x * 128, i0 = blockIdx.y * 128, b = blockIdx.z;
  const int tid = threadIdx.x;
  const int lane = tid & 63, wave = tid >> 6;
  const int wm = wave >> 1, wn = wave & 1;
  const int r16 = lane & 15, kg = lane >> 4;

  f32x4 acc[4][4];
#pragma unroll
  for (int mf = 0; mf < 4; mf++)
#pragma unroll
    for (int nf = 0; nf < 4; nf++) acc[mf][nf] = (f32x4){0.f, 0.f, 0.f, 0.f};

  const float* qb = q + (size_t)(b * SEQN + i0) * DD;
  const float* kb = kmat + (size_t)(b * SEQN + j0) * DD;

  for (int ks = 0; ks < 16; ks++) {
    const int k0 = ks * 32;
#pragma unroll
    for (int rep = 0; rep < 4; rep++) {
      int f = rep * 256 + tid;
      int row = f >> 3, c4 = f & 7;
      f32x4 xa = *(const f32x4*)(qb + (size_t)row * DD + k0 + c4 * 4);
      f32x4 xb = *(const f32x4*)(kb + (size_t)row * DD + k0 + c4 * 4);
      h16x4 ha = {(_Float16)xa[0], (_Float16)xa[1], (_Float16)xa[2], (_Float16)xa[3]};
      h16x4 hb = {(_Float16)xb[0], (_Float16)xb[1], (_Float16)xb[2], (_Float16)xb[3]};
      *(h16x4*)(smem + swzw(row, c4)) = ha;
      *(h16x4*)(smem + 8192 + swzw(row, c4)) = hb;
    }
    __syncthreads();
    h16x8 af[4], bf[4];
#pragma unroll
    for (int mf = 0; mf < 4; mf++)
      af[mf] = *(const h16x8*)(smem + swzr(wm * 64 + mf * 16 + r16, kg));
#pragma unroll
    for (int nf = 0; nf < 4; nf++)
      bf[nf] = *(const h16x8*)(smem + 8192 + swzr(wn * 64 + nf * 16 + r16, kg));
#pragma unroll
    for (int mf = 0; mf < 4; mf++)
#pragma unroll
      for (int nf = 0; nf < 4; nf++)
        acc[mf][nf] = __builtin_amdgcn_mfma_f32_16x16x32_f16(af[mf], bf[nf], acc[mf][nf], 0, 0, 0);
    __syncthreads();
  }

#pragma unroll
  for (int mf = 0; mf < 4; mf++)
#pragma unroll
    for (int nf = 0; nf < 4; nf++)
#pragma unroll
      for (int r = 0; r < 4; r++) {
        int ii = wm * 64 + mf * 16 + kg * 4 + r;
        int jj = wn * 64 + nf * 16 + r16;
        S[(size_t)(b * SEQN + i0 + ii) * SEQN + j0 + jj] = acc[mf][nf][r];
      }
}

// --- rel scores: S[b,i,j] += q[b,i] . w_k[(N-1)-i+j]  (band GEMM + scatter) --
__global__ __launch_bounds__(256) void score_rel_k(const float* __restrict__ q,
                                                   const float* __restrict__ wk,
                                                   float* __restrict__ S) {
  __shared__ __align__(16) char smem[16384];
  const int z = blockIdx.x;           // band tile 0..16
  const int i0 = blockIdx.y * 128, b = blockIdx.z;
  const int tid = threadIdx.x;
  const int lane = tid & 63, wave = tid >> 6;
  const int wm = wave >> 1, wn = wave & 1;
  const int r16 = lane & 15, kg = lane >> 4;
  const int tmin = SEQN - 128 - i0;   // first band row in w table

  f32x4 acc[4][4];
#pragma unroll
  for (int mf = 0; mf < 4; mf++)
#pragma unroll
    for (int nf = 0; nf < 4; nf++) acc[mf][nf] = (f32x4){0.f, 0.f, 0.f, 0.f};

  const float* qb = q + (size_t)(b * SEQN + i0) * DD;

  for (int ks = 0; ks < 16; ks++) {
    const int k0 = ks * 32;
#pragma unroll
    for (int rep = 0; rep < 4; rep++) {
      int f = rep * 256 + tid;
      int row = f >> 3, c4 = f & 7;
      f32x4 xa = *(const f32x4*)(qb + (size_t)row * DD + k0 + c4 * 4);
      int tr = tmin + z * 128 + row;
      if (tr > WROWS - 1) tr = WROWS - 1;       // clamp; results predicated off
      f32x4 xb = *(const f32x4*)(wk + (size_t)tr * DD + k0 + c4 * 4);
      h16x4 ha = {(_Float16)xa[0], (_Float16)xa[1], (_Float16)xa[2], (_Float16)xa[3]};
      h16x4 hb = {(_Float16)xb[0], (_Float16)xb[1], (_Float16)xb[2], (_Float16)xb[3]};
      *(h16x4*)(smem + swzw(row, c4)) = ha;
      *(h16x4*)(smem + 8192 + swzw(row, c4)) = hb;
    }
    __syncthreads();
    h16x8 af[4], bf[4];
#pragma unroll
    for (int mf = 0; mf < 4; mf++)
      af[mf] = *(const h16x8*)(smem + swzr(wm * 64 + mf * 16 + r16, kg));
#pragma unroll
    for (int nf = 0; nf < 4; nf++)
      bf[nf] = *(const h16x8*)(smem + 8192 + swzr(wn * 64 + nf * 16 + r16, kg));
#pragma unroll
    for (int mf = 0; mf < 4; mf++)
#pragma unroll
      for (int nf = 0; nf < 4; nf++)
        acc[mf][nf] = __builtin_amdgcn_mfma_f32_16x16x32_f16(af[mf], bf[nf], acc[mf][nf], 0, 0, 0);
    __syncthreads();
  }

  // scatter-add: band col bc -> j = bc + i' - 127
#pragma unroll
  for (int mf = 0; mf < 4; mf++)
#pragma unroll
    for (int nf = 0; nf < 4; nf++) {
      int bcg = z * 128 + wn * 64 + nf * 16 + r16;
#pragma unroll
      for (int r = 0; r < 4; r++) {
        int ii = wm * 64 + mf * 16 + kg * 4 + r;
        int j = bcg + ii - 127;
        if (bcg <= 2174 && j >= 0 && j < SEQN) {
          S[(size_t)(b * SEQN + i0 + ii) * SEQN + j] += acc[mf][nf][r];
        }
      }
    }
}

// ---------------- softmax over rows of S (in place -> p) --------------------
__global__ __launch_bounds__(256) void softmax_rows_k(float* __restrict__ S) {
  const int wid = threadIdx.x >> 6, lane = threadIdx.x & 63;
  const size_t row = (size_t)blockIdx.x * 4 + wid;
  float* p = S + row * SEQN;
  f32x4 x[8];
  float m = -3.4e38f;
#pragma unroll
  for (int c = 0; c < 8; c++) {
    x[c] = *(const f32x4*)(p + c * 256 + lane * 4);
    m = fmaxf(m, fmaxf(fmaxf(x[c][0], x[c][1]), fmaxf(x[c][2], x[c][3])));
  }
#pragma unroll
  for (int off = 32; off > 0; off >>= 1) m = fmaxf(m, __shfl_xor(m, off));
  float s = 0.f;
#pragma unroll
  for (int c = 0; c < 8; c++)
#pragma unroll
    for (int e = 0; e < 4; e++) {
      x[c][e] = __expf(x[c][e] - m);
      s += x[c][e];
    }
#pragma unroll
  for (int off = 32; off > 0; off >>= 1) s += __shfl_xor(s, off);
  float inv = 1.f / s;
#pragma unroll
  for (int c = 0; c < 8; c++) {
    x[c][0] *= inv; x[c][1] *= inv; x[c][2] *= inv; x[c][3] *= inv;
    *(f32x4*)(p + c * 256 + lane * 4) = x[c];
  }
}

// ------- out = p.v + skew(p).w_v  (two K-loops into one accumulator) --------
__global__ __launch_bounds__(256) void out_gemm_k(const float* __restrict__ S,
                                                  const _Float16* __restrict__ vT,
                                                  const _Float16* __restrict__ wvT,
                                                  float* __restrict__ outp) {
  __shared__ __align__(16) char smem[16384];
  const int d0 = blockIdx.x * 128, i0 = blockIdx.y * 128, b = blockIdx.z;
  const int tid = threadIdx.x;
  const int lane = tid & 63, wave = tid >> 6;
  const int wm = wave >> 1, wn = wave & 1;
  const int r16 = lane & 15, kg = lane >> 4;

  f32x4 acc[4][4];
#pragma unroll
  for (int mf = 0; mf < 4; mf++)
#pragma unroll
    for (int nf = 0; nf < 4; nf++) acc[mf][nf] = (f32x4){0.f, 0.f, 0.f, 0.f};

  const float* pb = S + (size_t)(b * SEQN + i0) * SEQN;
  const _Float16* vb = vT + (size_t)(b * DD + d0) * SEQN;

  // K-loop 1: out += p . v   (K dim = j)
  for (int ks = 0; ks < 64; ks++) {
    const int k0 = ks * 32;
#pragma unroll
    for (int rep = 0; rep < 4; rep++) {
      int f = rep * 256 + tid;
      int row = f >> 3, c4 = f & 7;
      f32x4 xa = *(const f32x4*)(pb + (size_t)row * SEQN + k0 + c4 * 4);
      h16x4 ha = {(_Float16)xa[0], (_Float16)xa[1], (_Float16)xa[2], (_Float16)xa[3]};
      *(h16x4*)(smem + swzw(row, c4)) = ha;
      h16x4 hb = *(const h16x4*)(vb + (size_t)row * SEQN + k0 + c4 * 4);
      *(h16x4*)(smem + 8192 + swzw(row, c4)) = hb;
    }
    __syncthreads();
    h16x8 af[4], bf[4];
#pragma unroll
    for (int mf = 0; mf < 4; mf++)
      af[mf] = *(const h16x8*)(smem + swzr(wm * 64 + mf * 16 + r16, kg));
#pragma unroll
    for (int nf = 0; nf < 4; nf++)
      bf[nf] = *(const h16x8*)(smem + 8192 + swzr(wn * 64 + nf * 16 + r16, kg));
#pragma unroll
    for (int mf = 0; mf < 4; mf++)
#pragma unroll
      for (int nf = 0; nf < 4; nf++)
        acc[mf][nf] = __builtin_amdgcn_mfma_f32_16x16x32_f16(af[mf], bf[nf], acc[mf][nf], 0, 0, 0);
    __syncthreads();
  }

  // K-loop 2: out += skew(p) . w_v   (K dim = band col bc; A[row][bc] = p[row][bc+row-127])
  const int tmin = SEQN - 128 - i0;
  const _Float16* wb = wvT + (size_t)d0 * WPAD + tmin;
  for (int ks = 0; ks < 68; ks++) {
    const int k0 = ks * 32;
#pragma unroll
    for (int rep = 0; rep < 4; rep++) {
      int f = rep * 256 + tid;
      int row = f >> 3, c4 = f & 7;
      int jb = k0 + c4 * 4 + row - 127;
      const float* pr = pb + (size_t)row * SEQN;
      h16x4 ha;
#pragma unroll
      for (int e = 0; e < 4; e++) {
        int j = jb + e;
        float val = (j >= 0 && j < SEQN) ? pr[j] : 0.f;
        ha[e] = (_Float16)val;
      }
      *(h16x4*)(smem + swzw(row, c4)) = ha;
      h16x4 hb = *(const h16x4*)(wb + (size_t)row * WPAD + k0 + c4 * 4);
      *(h16x4*)(smem + 8192 + swzw(row, c4)) = hb;
    }
    __syncthreads();
    h16x8 af[4], bf[4];
#pragma unroll
    for (int mf = 0; mf < 4; mf++)
      af[mf] = *(const h16x8*)(smem + swzr(wm * 64 + mf * 16 + r16, kg));
#pragma unroll
    for (int nf = 0; nf < 4; nf++)
      bf[nf] = *(const h16x8*)(smem + 8192 + swzr(wn * 64 + nf * 16 + r16, kg));
#pragma unroll
    for (int mf = 0; mf < 4; mf++)
#pragma unroll
      for (int nf = 0; nf < 4; nf++)
        acc[mf][nf] = __builtin_amdgcn_mfma_f32_16x16x32_f16(af[mf], bf[nf], acc[mf][nf], 0, 0, 0);
    __syncthreads();
  }

#pragma unroll
  for (int mf = 0; mf < 4; mf++)
#pragma unroll
    for (int nf = 0; nf < 4; nf++)
#pragma unroll
      for (int r = 0; r < 4; r++) {
        int ii = wm * 64 + mf * 16 + kg * 4 + r;
        int dd = wn * 64 + nf * 16 + r16;
        outp[(size_t)(b * SEQN + i0 + ii) * DD + d0 + dd] = acc[mf][nf][r];
      }
}

extern "C" void kernel_launch(void* const* d_in, const int* in_sizes, int n_in,
                              void* d_out, int out_size, void* d_ws, size_t ws_size,
                              hipStream_t stream) {
  const float* q  = (const float*)d_in[0];
  const float* k  = (const float*)d_in[1];
  const float* v  = (const float*)d_in[2];
  const float* wk = (const float*)d_in[3];
  const float* wv = (const float*)d_in[4];

  float* outp = (float*)d_out;
  float* S    = outp + (size_t)NB * SEQN * DD;   // p region of d_out, used as S scratch

  // workspace: vT [B,D,N] f16 (16.78 MB) + wvT [512,4096] f16 (4.19 MB) = 20.97 MB
  _Float16* vT  = (_Float16*)d_ws;
  _Float16* wvT = vT + (size_t)NB * DD * SEQN;

  transpose_v_k <<<dim3(DD / 32, SEQN / 32, NB), 256, 0, stream>>>(v, vT);
  transpose_wv_k<<<dim3(DD / 32, 128),           256, 0, stream>>>(wv, wvT);
  score_base_k  <<<dim3(SEQN / 128, SEQN / 128, NB), 256, 0, stream>>>(q, k, S);
  score_rel_k   <<<dim3(17, SEQN / 128, NB),     256, 0, stream>>>(q, wk, S);
  softmax_rows_k<<<dim3(NB * SEQN / 4),          256, 0, stream>>>(S);
  out_gemm_k    <<<dim3(DD / 128, SEQN / 128, NB), 256, 0, stream>>>(S, vT, wvT, outp);
}

// Round 5
// 466.699 us; speedup vs baseline: 1.6769x; 1.6769x over previous
//
#include <hip/hip_runtime.h>

// RelativeAttention B=8, N=2048, D=512, fp32 in, (out[B,N,D], p[B,N,N]) fp32 out.
//
// Round-5: bisection round. Rounds 2-4 failed with BIT-IDENTICAL absmax under
// three different staging mechanisms => the shared f16 data chain (cvt/ph/ps/
// providers) is buggy, not the schedules. This round is round-1-verbatim
// (proven: absmax 0.0859) EXCEPT out_gemm, which keeps round-1's exact
// address algebra + inputs (p fp32, vT, wvT) but adopts the round-4 schedule:
// reg-prefetch one K-step ahead, 2x16KB LDS double buffer, one barrier per
// step, XCD-aware block decode. Schedule proven equivalent by round-4's
// bit-identity; data path proven by round-1.

#define SEQN 2048
#define DD   512
#define NB   8
#define WROWS 4095   // 2N-1
#define WPAD  4096   // padded row stride for wvT

typedef float     f32x4 __attribute__((ext_vector_type(4)));
typedef _Float16  h16x4 __attribute__((ext_vector_type(4)));
typedef _Float16  h16x8 __attribute__((ext_vector_type(8)));

__device__ __forceinline__ unsigned swzw(int row, int c4) {
  unsigned b = (unsigned)(row * 64 + c4 * 8);
  return b ^ (((unsigned)row & 6u) << 3);
}
__device__ __forceinline__ unsigned swzr(int row, int kg) {
  unsigned b = (unsigned)(row * 64 + kg * 16);
  return b ^ (((unsigned)row & 6u) << 3);
}

// ---------------- transpose v [B,N,D] f32 -> vT [B,D,N] f16 ----------------
__global__ __launch_bounds__(256) void transpose_v_k(const float* __restrict__ v,
                                                     _Float16* __restrict__ vT) {
  __shared__ float tile[32][33];
  const int d0 = blockIdx.x * 32, j0 = blockIdx.y * 32, b = blockIdx.z;
  const int tid = threadIdx.x;
#pragma unroll
  for (int rep = 0; rep < 4; rep++) {
    int idx = rep * 256 + tid;
    int rr = idx >> 5, cc = idx & 31;
    tile[rr][cc] = v[((size_t)(b * SEQN + j0 + rr)) * DD + d0 + cc];
  }
  __syncthreads();
#pragma unroll
  for (int rep = 0; rep < 4; rep++) {
    int idx = rep * 256 + tid;
    int rr = idx >> 5, cc = idx & 31;
    vT[((size_t)(b * DD + d0 + rr)) * SEQN + j0 + cc] = (_Float16)tile[cc][rr];
  }
}

// ------------- transpose w_v [4095,512] f32 -> wvT [512,4096] f16 -----------
__global__ __launch_bounds__(256) void transpose_wv_k(const float* __restrict__ wv,
                                                      _Float16* __restrict__ wvT) {
  __shared__ float tile[32][33];
  const int d0 = blockIdx.x * 32, r0 = blockIdx.y * 32;
  const int tid = threadIdx.x;
#pragma unroll
  for (int rep = 0; rep < 4; rep++) {
    int idx = rep * 256 + tid;
    int rr = idx >> 5, cc = idx & 31;
    float val = 0.f;
    if (r0 + rr < WROWS) val = wv[(size_t)(r0 + rr) * DD + d0 + cc];
    tile[rr][cc] = val;
  }
  __syncthreads();
#pragma unroll
  for (int rep = 0; rep < 4; rep++) {
    int idx = rep * 256 + tid;
    int rr = idx >> 5, cc = idx & 31;
    wvT[(size_t)(d0 + rr) * WPAD + r0 + cc] = (_Float16)tile[cc][rr];
  }
}

// ---------------- base scores: S[b,i,j] = sum_d q[b,i,d] k[b,j,d] -----------
__global__ __launch_bounds__(256) void score_base_k(const float* __restrict__ q,
                                                    const float* __restrict__ kmat,
                                                    float* __restrict__ S) {
  __shared__ __align__(16) char smem[16384];
  const int j0 = blockIdx.x * 128, i0 = blockIdx.y * 128, b = blockIdx.z;
  const int tid = threadIdx.x;
  const int lane = tid & 63, wave = tid >> 6;
  const int wm = wave >> 1, wn = wave & 1;
  const int r16 = lane & 15, kg = lane >> 4;

  f32x4 acc[4][4];
#pragma unroll
  for (int mf = 0; mf < 4; mf++)
#pragma unroll
    for (int nf = 0; nf < 4; nf++) acc[mf][nf] = (f32x4){0.f, 0.f, 0.f, 0.f};

  const float* qb = q + (size_t)(b * SEQN + i0) * DD;
  const float* kb = kmat + (size_t)(b * SEQN + j0) * DD;

  for (int ks = 0; ks < 16; ks++) {
    const int k0 = ks * 32;
#pragma unroll
    for (int rep = 0; rep < 4; rep++) {
      int f = rep * 256 + tid;
      int row = f >> 3, c4 = f & 7;
      f32x4 xa = *(const f32x4*)(qb + (size_t)row * DD + k0 + c4 * 4);
      f32x4 xb = *(const f32x4*)(kb + (size_t)row * DD + k0 + c4 * 4);
      h16x4 ha = {(_Float16)xa[0], (_Float16)xa[1], (_Float16)xa[2], (_Float16)xa[3]};
      h16x4 hb = {(_Float16)xb[0], (_Float16)xb[1], (_Float16)xb[2], (_Float16)xb[3]};
      *(h16x4*)(smem + swzw(row, c4)) = ha;
      *(h16x4*)(smem + 8192 + swzw(row, c4)) = hb;
    }
    __syncthreads();
    h16x8 af[4], bf[4];
#pragma unroll
    for (int mf = 0; mf < 4; mf++)
      af[mf] = *(const h16x8*)(smem + swzr(wm * 64 + mf * 16 + r16, kg));
#pragma unroll
    for (int nf = 0; nf < 4; nf++)
      bf[nf] = *(const h16x8*)(smem + 8192 + swzr(wn * 64 + nf * 16 + r16, kg));
#pragma unroll
    for (int mf = 0; mf < 4; mf++)
#pragma unroll
      for (int nf = 0; nf < 4; nf++)
        acc[mf][nf] = __builtin_amdgcn_mfma_f32_16x16x32_f16(af[mf], bf[nf], acc[mf][nf], 0, 0, 0);
    __syncthreads();
  }

#pragma unroll
  for (int mf = 0; mf < 4; mf++)
#pragma unroll
    for (int nf = 0; nf < 4; nf++)
#pragma unroll
      for (int r = 0; r < 4; r++) {
        int ii = wm * 64 + mf * 16 + kg * 4 + r;
        int jj = wn * 64 + nf * 16 + r16;
        S[(size_t)(b * SEQN + i0 + ii) * SEQN + j0 + jj] = acc[mf][nf][r];
      }
}

// --- rel scores: S[b,i,j] += q[b,i] . w_k[(N-1)-i+j]  (band GEMM + scatter) --
__global__ __launch_bounds__(256) void score_rel_k(const float* __restrict__ q,
                                                   const float* __restrict__ wk,
                                                   float* __restrict__ S) {
  __shared__ __align__(16) char smem[16384];
  const int z = blockIdx.x;           // band tile 0..16
  const int i0 = blockIdx.y * 128, b = blockIdx.z;
  const int tid = threadIdx.x;
  const int lane = tid & 63, wave = tid >> 6;
  const int wm = wave >> 1, wn = wave & 1;
  const int r16 = lane & 15, kg = lane >> 4;
  const int tmin = SEQN - 128 - i0;   // first band row in w table

  f32x4 acc[4][4];
#pragma unroll
  for (int mf = 0; mf < 4; mf++)
#pragma unroll
    for (int nf = 0; nf < 4; nf++) acc[mf][nf] = (f32x4){0.f, 0.f, 0.f, 0.f};

  const float* qb = q + (size_t)(b * SEQN + i0) * DD;

  for (int ks = 0; ks < 16; ks++) {
    const int k0 = ks * 32;
#pragma unroll
    for (int rep = 0; rep < 4; rep++) {
      int f = rep * 256 + tid;
      int row = f >> 3, c4 = f & 7;
      f32x4 xa = *(const f32x4*)(qb + (size_t)row * DD + k0 + c4 * 4);
      int tr = tmin + z * 128 + row;
      if (tr > WROWS - 1) tr = WROWS - 1;       // clamp; results predicated off
      f32x4 xb = *(const f32x4*)(wk + (size_t)tr * DD + k0 + c4 * 4);
      h16x4 ha = {(_Float16)xa[0], (_Float16)xa[1], (_Float16)xa[2], (_Float16)xa[3]};
      h16x4 hb = {(_Float16)xb[0], (_Float16)xb[1], (_Float16)xb[2], (_Float16)xb[3]};
      *(h16x4*)(smem + swzw(row, c4)) = ha;
      *(h16x4*)(smem + 8192 + swzw(row, c4)) = hb;
    }
    __syncthreads();
    h16x8 af[4], bf[4];
#pragma unroll
    for (int mf = 0; mf < 4; mf++)
      af[mf] = *(const h16x8*)(smem + swzr(wm * 64 + mf * 16 + r16, kg));
#pragma unroll
    for (int nf = 0; nf < 4; nf++)
      bf[nf] = *(const h16x8*)(smem + 8192 + swzr(wn * 64 + nf * 16 + r16, kg));
#pragma unroll
    for (int mf = 0; mf < 4; mf++)
#pragma unroll
      for (int nf = 0; nf < 4; nf++)
        acc[mf][nf] = __builtin_amdgcn_mfma_f32_16x16x32_f16(af[mf], bf[nf], acc[mf][nf], 0, 0, 0);
    __syncthreads();
  }

  // scatter-add: band col bc -> j = bc + i' - 127
#pragma unroll
  for (int mf = 0; mf < 4; mf++)
#pragma unroll
    for (int nf = 0; nf < 4; nf++) {
      int bcg = z * 128 + wn * 64 + nf * 16 + r16;
#pragma unroll
      for (int r = 0; r < 4; r++) {
        int ii = wm * 64 + mf * 16 + kg * 4 + r;
        int j = bcg + ii - 127;
        if (bcg <= 2174 && j >= 0 && j < SEQN) {
          S[(size_t)(b * SEQN + i0 + ii) * SEQN + j] += acc[mf][nf][r];
        }
      }
    }
}

// ---------------- softmax over rows of S (in place -> p) --------------------
__global__ __launch_bounds__(256) void softmax_rows_k(float* __restrict__ S) {
  const int wid = threadIdx.x >> 6, lane = threadIdx.x & 63;
  const size_t row = (size_t)blockIdx.x * 4 + wid;
  float* p = S + row * SEQN;
  f32x4 x[8];
  float m = -3.4e38f;
#pragma unroll
  for (int c = 0; c < 8; c++) {
    x[c] = *(const f32x4*)(p + c * 256 + lane * 4);
    m = fmaxf(m, fmaxf(fmaxf(x[c][0], x[c][1]), fmaxf(x[c][2], x[c][3])));
  }
#pragma unroll
  for (int off = 32; off > 0; off >>= 1) m = fmaxf(m, __shfl_xor(m, off));
  float s = 0.f;
#pragma unroll
  for (int c = 0; c < 8; c++)
#pragma unroll
    for (int e = 0; e < 4; e++) {
      x[c][e] = __expf(x[c][e] - m);
      s += x[c][e];
    }
#pragma unroll
  for (int off = 32; off > 0; off >>= 1) s += __shfl_xor(s, off);
  float inv = 1.f / s;
#pragma unroll
  for (int c = 0; c < 8; c++) {
    x[c][0] *= inv; x[c][1] *= inv; x[c][2] *= inv; x[c][3] *= inv;
    *(f32x4*)(p + c * 256 + lane * 4) = x[c];
  }
}

// ------- out = p.v + skew(p).w_v  — round-1 algebra, round-4 schedule -------
// 132 K-steps: t in [0,64) = p.v ; t in [64,132) = skew(p).w_v.
// Reg-prefetch one step ahead; 2x16KB LDS double buffer; 1 barrier/step.
__global__ __launch_bounds__(256) void out_gemm3_k(const float* __restrict__ S,
                                                   const _Float16* __restrict__ vT,
                                                   const _Float16* __restrict__ wvT,
                                                   float* __restrict__ outp) {
  __shared__ __align__(16) char smem[32768];
  // XCD-aware decode: 4 d-tiles sharing (i0,b)'s p rows land on one XCD.
  const int bid = blockIdx.x;
  const int xcd = bid & 7, rr = bid >> 3;
  const int x = rr & 3, s8 = rr >> 2;
  const int sidx = xcd + 8 * s8;             // [0,128): (i-tile, b), bijective
  const int d0 = x * 128, i0 = (sidx & 15) * 128, b = sidx >> 4;
  const int tid = threadIdx.x, lane = tid & 63, wave = tid >> 6;
  const int wm = wave >> 1, wn = wave & 1, r16 = lane & 15, kg = lane >> 4;
  const int tmin = SEQN - 128 - i0;

  const float*    pb = S  + (size_t)(b * SEQN + i0) * SEQN;
  const _Float16* vb = vT + (size_t)(b * DD + d0) * SEQN;
  const _Float16* wb = wvT + (size_t)d0 * WPAD + tmin;

  f32x4 acc[4][4];
#pragma unroll
  for (int mf = 0; mf < 4; mf++)
#pragma unroll
    for (int nf = 0; nf < 4; nf++) acc[mf][nf] = (f32x4){0.f, 0.f, 0.f, 0.f};

  f32x4 ra[4];      // staged A (f32, cvt at LDS-write time — round-1 order)
  h16x4 rbv[4];     // staged B (f16)

  auto LOADREGS = [&](int t) {
    if (t < 64) {
      const int k0 = t * 32;
#pragma unroll
      for (int rep = 0; rep < 4; rep++) {
        int f = rep * 256 + tid, row = f >> 3, c4 = f & 7;
        ra[rep]  = *(const f32x4*)(pb + (size_t)row * SEQN + k0 + c4 * 4);
        rbv[rep] = *(const h16x4*)(vb + (size_t)row * SEQN + k0 + c4 * 4);
      }
    } else {
      const int k0 = (t - 64) * 32;
#pragma unroll
      for (int rep = 0; rep < 4; rep++) {
        int f = rep * 256 + tid, row = f >> 3, c4 = f & 7;
        int jb = k0 + c4 * 4 + row - 127;
        const float* pr = pb + (size_t)row * SEQN;
        f32x4 v4;
#pragma unroll
        for (int e = 0; e < 4; e++) {
          int j = jb + e;
          v4[e] = (j >= 0 && j < SEQN) ? pr[j] : 0.f;
        }
        ra[rep]  = v4;
        rbv[rep] = *(const h16x4*)(wb + (size_t)row * WPAD + k0 + c4 * 4);
      }
    }
  };
  auto WRITE = [&](char* lb) {
#pragma unroll
    for (int rep = 0; rep < 4; rep++) {
      int f = rep * 256 + tid, row = f >> 3, c4 = f & 7;
      h16x4 ha = {(_Float16)ra[rep][0], (_Float16)ra[rep][1],
                  (_Float16)ra[rep][2], (_Float16)ra[rep][3]};
      *(h16x4*)(lb + swzw(row, c4)) = ha;
      *(h16x4*)(lb + 8192 + swzw(row, c4)) = rbv[rep];
    }
  };

  LOADREGS(0);
  WRITE(smem);
  LOADREGS(1);                 // tile 1 pending in regs
  __syncthreads();             // tile 0 visible

  for (int t = 0; t < 132; t++) {
    char* lb = smem + (t & 1) * 16384;
    if (t + 1 < 132) WRITE(smem + ((t + 1) & 1) * 16384);   // WAR-safe: reads of that buf retired last iter
    h16x8 af[4], bf[4];
#pragma unroll
    for (int mf = 0; mf < 4; mf++)
      af[mf] = *(const h16x8*)(lb + swzr(wm * 64 + mf * 16 + r16, kg));
#pragma unroll
    for (int nf = 0; nf < 4; nf++)
      bf[nf] = *(const h16x8*)(lb + 8192 + swzr(wn * 64 + nf * 16 + r16, kg));
    if (t + 2 < 132) LOADREGS(t + 2);                        // issue early, hide latency
#pragma unroll
    for (int mf = 0; mf < 4; mf++)
#pragma unroll
      for (int nf = 0; nf < 4; nf++)
        acc[mf][nf] = __builtin_amdgcn_mfma_f32_16x16x32_f16(af[mf], bf[nf], acc[mf][nf], 0, 0, 0);
    __syncthreads();
  }

#pragma unroll
  for (int mf = 0; mf < 4; mf++)
#pragma unroll
    for (int nf = 0; nf < 4; nf++)
#pragma unroll
      for (int r = 0; r < 4; r++) {
        int ii = wm * 64 + mf * 16 + kg * 4 + r;
        int dd = wn * 64 + nf * 16 + r16;
        outp[(size_t)(b * SEQN + i0 + ii) * DD + d0 + dd] = acc[mf][nf][r];
      }
}

extern "C" void kernel_launch(void* const* d_in, const int* in_sizes, int n_in,
                              void* d_out, int out_size, void* d_ws, size_t ws_size,
                              hipStream_t stream) {
  const float* q  = (const float*)d_in[0];
  const float* k  = (const float*)d_in[1];
  const float* v  = (const float*)d_in[2];
  const float* wk = (const float*)d_in[3];
  const float* wv = (const float*)d_in[4];

  float* outp = (float*)d_out;
  float* S    = outp + (size_t)NB * SEQN * DD;   // p region of d_out doubles as S

  // workspace: vT [B,D,N] f16 (16.78 MB) + wvT [512,4096] f16 (4.19 MB)
  _Float16* vT  = (_Float16*)d_ws;
  _Float16* wvT = vT + (size_t)NB * DD * SEQN;

  transpose_v_k <<<dim3(DD / 32, SEQN / 32, NB), 256, 0, stream>>>(v, vT);
  transpose_wv_k<<<dim3(DD / 32, 128),           256, 0, stream>>>(wv, wvT);
  score_base_k  <<<dim3(SEQN / 128, SEQN / 128, NB), 256, 0, stream>>>(q, k, S);
  score_rel_k   <<<dim3(17, SEQN / 128, NB),     256, 0, stream>>>(q, wk, S);
  softmax_rows_k<<<dim3(NB * SEQN / 4),          256, 0, stream>>>(S);
  out_gemm3_k   <<<dim3(512),                    256, 0, stream>>>(S, vT, wvT, outp);
}